// Round 1
// baseline (152.538 us; speedup 1.0000x reference)
//
#include <hip/hip_runtime.h>
#include <hip/hip_bf16.h>
#include <stdint.h>

typedef __bf16 bf16_t;
typedef __bf16 bf16x8 __attribute__((ext_vector_type(8)));
typedef __bf16 bf16x4 __attribute__((ext_vector_type(4)));
typedef float  f32x4  __attribute__((ext_vector_type(4)));

#define DEV __device__ __forceinline__

static constexpr int NTOK = 2048;
static constexpr int DIM  = 1024;
static constexpr int NH   = 16;
static constexpr int DH   = 64;
static constexpr int QKVN = 3072;

DEV void gload_lds16(const void* g, void* l) {
  __builtin_amdgcn_global_load_lds(
      (__attribute__((address_space(1))) void*)(g),
      (__attribute__((address_space(3))) void*)(l), 16, 0, 0);
}

DEV float bf2f(bf16_t b) { return (float)b; }

// ---------------- LayerNorm + cast to bf16 ----------------
__global__ __launch_bounds__(256) void k_ln(const float* __restrict__ x,
                                            const float* __restrict__ gamma,
                                            const float* __restrict__ beta,
                                            bf16_t* __restrict__ xn) {
  const int row = blockIdx.x;
  const int t = threadIdx.x;
  const float4* x4 = reinterpret_cast<const float4*>(x);
  float4 v = x4[(size_t)row * 256 + t];
  float s  = v.x + v.y + v.z + v.w;
  float s2 = v.x * v.x + v.y * v.y + v.z * v.z + v.w * v.w;
#pragma unroll
  for (int o = 1; o < 64; o <<= 1) {
    s  += __shfl_xor(s, o, 64);
    s2 += __shfl_xor(s2, o, 64);
  }
  __shared__ float red[8];
  const int w = t >> 6, lane = t & 63;
  if (lane == 0) { red[w] = s; red[4 + w] = s2; }
  __syncthreads();
  s  = red[0] + red[1] + red[2] + red[3];
  s2 = red[4] + red[5] + red[6] + red[7];
  const float mu  = s * (1.0f / 1024.0f);
  const float var = s2 * (1.0f / 1024.0f) - mu * mu;
  const float inv = rsqrtf(var + 1e-6f);
  const float4 g = reinterpret_cast<const float4*>(gamma)[t];
  const float4 b = reinterpret_cast<const float4*>(beta)[t];
  bf16x4 o;
  o[0] = (bf16_t)((v.x - mu) * inv * g.x + b.x);
  o[1] = (bf16_t)((v.y - mu) * inv * g.y + b.y);
  o[2] = (bf16_t)((v.z - mu) * inv * g.z + b.z);
  o[3] = (bf16_t)((v.w - mu) * inv * g.w + b.w);
  *reinterpret_cast<bf16x4*>(xn + (size_t)row * DIM + t * 4) = o;
}

// ---------------- transpose + cast fp32 MxN -> bf16 NxM ----------------
__global__ __launch_bounds__(256) void k_tc(const float* __restrict__ src,
                                            bf16_t* __restrict__ dst,
                                            int M, int N) {
  __shared__ float tile[64][65];
  const int c0 = blockIdx.x * 64;
  const int r0 = blockIdx.y * 64;
  const int tx = threadIdx.x & 63;
  const int ty = threadIdx.x >> 6;
#pragma unroll
  for (int i = 0; i < 16; ++i) {
    int r = ty + i * 4;
    tile[r][tx] = src[(size_t)(r0 + r) * N + c0 + tx];
  }
  __syncthreads();
#pragma unroll
  for (int i = 0; i < 16; ++i) {
    int r = ty + i * 4;
    dst[(size_t)(c0 + r) * M + r0 + tx] = (bf16_t)tile[tx][r];
  }
}

// ---------------- GEMM: C[M,N] = A[M,K] * Bt[N,K]^T (+bias), m97 structure ----------------
template <int F32OUT>
__global__ __launch_bounds__(256) void k_gemm_bt(const bf16_t* __restrict__ A,
                                                 const bf16_t* __restrict__ Bt,
                                                 bf16_t* __restrict__ Cb,
                                                 float* __restrict__ Cf,
                                                 const float* __restrict__ bias,
                                                 int M, int N, int K) {
  __shared__ alignas(16) bf16_t As[128 * 32];
  __shared__ alignas(16) bf16_t Bs[128 * 32];
  const int tid = threadIdx.x, lane = tid & 63, w = tid >> 6;
  const int bm = blockIdx.x * 128, bn = blockIdx.y * 128;
  const int wr = (w >> 1) * 64, wc = (w & 1) * 64;
  f32x4 acc[4][4];
#pragma unroll
  for (int i = 0; i < 4; ++i)
#pragma unroll
    for (int j = 0; j < 4; ++j) acc[i][j] = f32x4{0.f, 0.f, 0.f, 0.f};

  const int srow  = lane >> 2;        // 0..15
  const int scol8 = (lane & 3) * 8;   // element offset in K

  for (int kt = 0; kt < K; kt += 32) {
    __syncthreads();
#pragma unroll
    for (int it = 0; it < 2; ++it) {
      int seg = w * 2 + it;
      int ar = bm + seg * 16 + srow;
      int br = bn + seg * 16 + srow;
      gload_lds16(A  + (size_t)ar * K + kt + scol8, (char*)As + seg * 1024 + lane * 16);
      gload_lds16(Bt + (size_t)br * K + kt + scol8, (char*)Bs + seg * 1024 + lane * 16);
    }
    __syncthreads();
    bf16x8 af[4], bfr[4];
#pragma unroll
    for (int i = 0; i < 4; ++i) {
      int mrow = wr + i * 16 + (lane & 15);
      af[i] = *reinterpret_cast<const bf16x8*>((const char*)As + mrow * 64 + (lane >> 4) * 16);
    }
#pragma unroll
    for (int j = 0; j < 4; ++j) {
      int nrow = wc + j * 16 + (lane & 15);
      bfr[j] = *reinterpret_cast<const bf16x8*>((const char*)Bs + nrow * 64 + (lane >> 4) * 16);
    }
#pragma unroll
    for (int i = 0; i < 4; ++i)
#pragma unroll
      for (int j = 0; j < 4; ++j)
        acc[i][j] = __builtin_amdgcn_mfma_f32_16x16x32_bf16(af[i], bfr[j], acc[i][j], 0, 0, 0);
  }

#pragma unroll
  for (int i = 0; i < 4; ++i)
#pragma unroll
    for (int j = 0; j < 4; ++j)
#pragma unroll
      for (int r = 0; r < 4; ++r) {
        int mm = bm + wr + i * 16 + (lane >> 4) * 4 + r;
        int nn = bn + wc + j * 16 + (lane & 15);
        float val = acc[i][j][r];
        if (F32OUT)
          Cf[(size_t)mm * N + nn] = val + bias[nn];
        else
          Cb[(size_t)mm * N + nn] = (bf16_t)val;
      }
}

// ---------------- RoPE in-place on q,k of qkv (rows 1..N-1) ----------------
__global__ __launch_bounds__(256) void k_rope(bf16_t* __restrict__ qkv,
                                              const float* __restrict__ psin,
                                              const float* __restrict__ pcos) {
  const int i = blockIdx.x + 1;
  const int t = threadIdx.x;
#pragma unroll
  for (int itr = 0; itr < 4; ++itr) {
    int pidx = itr * 256 + t;          // 0..1023 pairs
    int half = pidx >> 9;              // 0=q, 1=k
    int pp   = pidx & 511;
    int hh = pp >> 5, tt = pp & 31;
    size_t off = (size_t)i * QKVN + half * 1024 + hh * 64 + tt * 2;
    float sn = psin[(size_t)(i - 1) * 32 + tt];
    float cs = pcos[(size_t)(i - 1) * 32 + tt];
    unsigned int u = *reinterpret_cast<const unsigned int*>(qkv + off);
    float x0 = bf2f(__builtin_bit_cast(bf16_t, (unsigned short)(u & 0xffffu)));
    float x1 = bf2f(__builtin_bit_cast(bf16_t, (unsigned short)(u >> 16)));
    unsigned short b0 = __builtin_bit_cast(unsigned short, (bf16_t)(x0 * cs - x1 * sn));
    unsigned short b1 = __builtin_bit_cast(unsigned short, (bf16_t)(x1 * cs + x0 * sn));
    *reinterpret_cast<unsigned int*>(qkv + off) = (unsigned int)b0 | ((unsigned int)b1 << 16);
  }
}

// ---------------- V transpose per head: qkv v-part -> Vt[h][d][n] ----------------
__global__ __launch_bounds__(256) void k_vtrans(const bf16_t* __restrict__ qkv,
                                                bf16_t* __restrict__ Vt) {
  __shared__ bf16_t tile[64][72];
  const int n0 = blockIdx.x * 64;
  const int h  = blockIdx.y;
  const int r  = threadIdx.x >> 2;   // 0..63
  const int cq = threadIdx.x & 3;    // 0..3 (16-wide chunks)
  const bf16_t* src = qkv + (size_t)(n0 + r) * QKVN + 2048 + h * DH + cq * 16;
  bf16x8 v0 = *reinterpret_cast<const bf16x8*>(src);
  bf16x8 v1 = *reinterpret_cast<const bf16x8*>(src + 8);
#pragma unroll
  for (int e = 0; e < 8; ++e) { tile[r][cq * 16 + e] = v0[e]; tile[r][cq * 16 + 8 + e] = v1[e]; }
  __syncthreads();
  const int d = r;
  bf16x8 o0, o1;
#pragma unroll
  for (int e = 0; e < 8; ++e) { o0[e] = tile[cq * 16 + e][d]; o1[e] = tile[cq * 16 + 8 + e][d]; }
  bf16_t* dst = Vt + ((size_t)h * DH + d) * NTOK + n0 + cq * 16;
  *reinterpret_cast<bf16x8*>(dst)     = o0;
  *reinterpret_cast<bf16x8*>(dst + 8) = o1;
}

// ---------------- flash attention ----------------
// grid: (NTOK/64, NH). 4 waves, each owns 16 q-rows. K/V tiles of 64 keys.
__global__ __launch_bounds__(256) void k_attn(const bf16_t* __restrict__ qkv,
                                              const bf16_t* __restrict__ Vt,
                                              const int* __restrict__ mask,
                                              bf16_t* __restrict__ Ob) {
  __shared__ alignas(16) bf16_t Ks[64 * 64];
  __shared__ alignas(16) bf16_t Vs[64 * 64];
  __shared__ alignas(16) bf16_t Ps[4][1024];
  __shared__ unsigned char padc[NTOK];

  const int h  = blockIdx.y;
  const int q0 = blockIdx.x * 64;
  const int tid = threadIdx.x, lane = tid & 63, w = tid >> 6;

  for (int j = tid; j < NTOK; j += 256)
    padc[j] = (j == 0) ? 1 : (unsigned char)(mask[j - 1] != 0);

  // Q fragments (16 rows per wave), rope already applied
  const int qrow = q0 + w * 16 + (lane & 15);
  bf16x8 qf[2];
  {
    const bf16_t* qp = qkv + (size_t)qrow * QKVN + h * DH + (lane >> 4) * 8;
    qf[0] = *reinterpret_cast<const bf16x8*>(qp);
    qf[1] = *reinterpret_cast<const bf16x8*>(qp + 32);
  }

  float m_run[4], l_run[4];
  f32x4 acc[4];
#pragma unroll
  for (int r = 0; r < 4; ++r) { m_run[r] = -1e30f; l_run[r] = 0.f; }
#pragma unroll
  for (int df = 0; df < 4; ++df) acc[df] = f32x4{0.f, 0.f, 0.f, 0.f};

  const float scale = 0.03125f;  // 1024^-0.5
  const int kmax = (q0 == 0) ? NTOK : (q0 + 64);
  const int srow = lane >> 3;    // 0..7
  const int scol = lane & 7;     // 16B unit within 128B row

  for (int k0 = 0; k0 < kmax; k0 += 64) {
    __syncthreads();
    // stage K (keys x dh) and Vt (dh x keys) tiles, XOR-swizzled via global source
#pragma unroll
    for (int it = 0; it < 2; ++it) {
      int seg = w * 2 + it;
      int row = seg * 8 + srow;
      int sw  = scol ^ (row & 7);
      gload_lds16(qkv + (size_t)(k0 + row) * QKVN + DIM + h * DH + sw * 8,
                  (char*)Ks + seg * 1024 + lane * 16);
      gload_lds16(Vt + ((size_t)h * DH + row) * NTOK + k0 + sw * 8,
                  (char*)Vs + seg * 1024 + lane * 16);
    }
    __syncthreads();

    // S = Q K^T  (16 rows x 64 keys per wave)
    f32x4 sfr[4];
#pragma unroll
    for (int jf = 0; jf < 4; ++jf) {
      f32x4 s = f32x4{0.f, 0.f, 0.f, 0.f};
      int jl = jf * 16 + (lane & 15);
#pragma unroll
      for (int ks = 0; ks < 2; ++ks) {
        int inrow = (ks * 64 + (lane >> 4) * 16) ^ ((jl & 7) << 4);
        bf16x8 kf = *reinterpret_cast<const bf16x8*>((const char*)Ks + jl * 128 + inrow);
        s = __builtin_amdgcn_mfma_f32_16x16x32_bf16(qf[ks], kf, s, 0, 0, 0);
      }
      sfr[jf] = s;
    }

    // mask + scale, row max
    float sv[4][4];
    float pmax[4] = {-1e30f, -1e30f, -1e30f, -1e30f};
#pragma unroll
    for (int jf = 0; jf < 4; ++jf) {
      int j = k0 + jf * 16 + (lane & 15);
      bool padj = padc[j] != 0;
#pragma unroll
      for (int r = 0; r < 4; ++r) {
        int i = q0 + w * 16 + (lane >> 4) * 4 + r;
        bool ok = padj && ((j <= i) || (i == 0));
        sv[jf][r] = ok ? sfr[jf][r] * scale : -1e30f;
        pmax[r] = fmaxf(pmax[r], sv[jf][r]);
      }
    }
#pragma unroll
    for (int o = 1; o < 16; o <<= 1)
#pragma unroll
      for (int r = 0; r < 4; ++r) pmax[r] = fmaxf(pmax[r], __shfl_xor(pmax[r], o, 64));

    // online softmax update
    float corr[4];
#pragma unroll
    for (int r = 0; r < 4; ++r) {
      float mnew = fmaxf(m_run[r], pmax[r]);
      corr[r] = __expf(m_run[r] - mnew);
      m_run[r] = mnew;
    }
    float rsum[4] = {0.f, 0.f, 0.f, 0.f};
#pragma unroll
    for (int jf = 0; jf < 4; ++jf)
#pragma unroll
      for (int r = 0; r < 4; ++r) {
        float pe = __expf(sv[jf][r] - m_run[r]);
        rsum[r] += pe;
        int m = (lane >> 4) * 4 + r;
        int jloc = jf * 16 + (lane & 15);
        *reinterpret_cast<bf16_t*>((char*)&Ps[w][0] + m * 128 + ((jloc * 2) ^ ((m & 7) << 4))) =
            (bf16_t)pe;
      }
#pragma unroll
    for (int o = 1; o < 16; o <<= 1)
#pragma unroll
      for (int r = 0; r < 4; ++r) rsum[r] += __shfl_xor(rsum[r], o, 64);
#pragma unroll
    for (int r = 0; r < 4; ++r) l_run[r] = l_run[r] * corr[r] + rsum[r];
#pragma unroll
    for (int df = 0; df < 4; ++df)
#pragma unroll
      for (int r = 0; r < 4; ++r) acc[df][r] *= corr[r];

    // O += P V
#pragma unroll
    for (int ks = 0; ks < 2; ++ks) {
      int mm = lane & 15;
      int inrow = (ks * 64 + (lane >> 4) * 16) ^ ((mm & 7) << 4);
      bf16x8 pa = *reinterpret_cast<const bf16x8*>((const char*)&Ps[w][0] + mm * 128 + inrow);
#pragma unroll
      for (int df = 0; df < 4; ++df) {
        int d = df * 16 + (lane & 15);
        int vin = (ks * 64 + (lane >> 4) * 16) ^ ((d & 7) << 4);
        bf16x8 vf = *reinterpret_cast<const bf16x8*>((const char*)Vs + d * 128 + vin);
        acc[df] = __builtin_amdgcn_mfma_f32_16x16x32_bf16(pa, vf, acc[df], 0, 0, 0);
      }
    }
  }

#pragma unroll
  for (int df = 0; df < 4; ++df)
#pragma unroll
    for (int r = 0; r < 4; ++r) {
      int i = q0 + w * 16 + (lane >> 4) * 4 + r;
      Ob[(size_t)i * DIM + h * DH + df * 16 + (lane & 15)] = (bf16_t)(acc[df][r] / l_run[r]);
    }
}

// ---------------- host ----------------
extern "C" void kernel_launch(void* const* d_in, const int* in_sizes, int n_in,
                              void* d_out, int out_size, void* d_ws, size_t ws_size,
                              hipStream_t stream) {
  const float* x       = (const float*)d_in[0];
  const float* pos_sin = (const float*)d_in[1];
  const float* pos_cos = (const float*)d_in[2];
  const int*   mask    = (const int*)d_in[3];
  const float* ln_s    = (const float*)d_in[4];
  const float* ln_b    = (const float*)d_in[5];
  const float* w_qkv   = (const float*)d_in[6];
  const float* w_out   = (const float*)d_in[7];
  const float* b_out   = (const float*)d_in[8];
  float* out = (float*)d_out;

  if (ws_size < 33554432u) return;

  char* ws = (char*)d_ws;
  bf16_t* xn  = (bf16_t*)(ws + 0);          //  4 MiB: 2048x1024
  bf16_t* qkv = (bf16_t*)(ws + 4194304);    // 12 MiB: 2048x3072
  bf16_t* Wqt = (bf16_t*)(ws + 16777216);   //  6 MiB: 3072x1024
  bf16_t* Wot = (bf16_t*)(ws + 23068672);   //  2 MiB: 1024x1024
  bf16_t* Vt  = (bf16_t*)(ws + 25165824);   //  4 MiB: 16x64x2048
  bf16_t* Ob  = (bf16_t*)(ws + 29360128);   //  4 MiB: 2048x1024

  k_ln<<<NTOK, 256, 0, stream>>>(x, ln_s, ln_b, xn);
  k_tc<<<dim3(48, 16), 256, 0, stream>>>(w_qkv, Wqt, 1024, 3072);
  k_tc<<<dim3(16, 16), 256, 0, stream>>>(w_out, Wot, 1024, 1024);
  k_gemm_bt<0><<<dim3(16, 24), 256, 0, stream>>>(xn, Wqt, qkv, nullptr, nullptr,
                                                 NTOK, QKVN, DIM);
  k_rope<<<NTOK - 1, 256, 0, stream>>>(qkv, pos_sin, pos_cos);
  k_vtrans<<<dim3(32, 16), 256, 0, stream>>>(qkv, Vt);
  k_attn<<<dim3(32, 16), 256, 0, stream>>>(qkv, Vt, mask, Ob);
  k_gemm_bt<1><<<dim3(16, 8), 256, 0, stream>>>(Ob, Wot, nullptr, out, b_out,
                                                NTOK, DIM, DIM);
}